// Round 3
// baseline (1688.900 us; speedup 1.0000x reference)
//
#include <hip/hip_runtime.h>

#define SEQ 8192
#define DIM 1024
#define SM_SCALE 0.03125f   // 1/sqrt(1024)

typedef unsigned short u16;
typedef float f32x4 __attribute__((ext_vector_type(4)));
typedef short bf16x8 __attribute__((ext_vector_type(8)));
typedef u16   u16x4 __attribute__((ext_vector_type(4)));

typedef __attribute__((address_space(1))) void as1_void;
typedef __attribute__((address_space(3))) void as3_void;

__device__ __forceinline__ u16 f2bf(float x) {
    unsigned u = __float_as_uint(x);
    u += 0x7fffu + ((u >> 16) & 1u);           // round-to-nearest-even
    return (u16)(u >> 16);
}
__device__ __forceinline__ float bf2f(u16 b) {
    return __uint_as_float(((unsigned)b) << 16);
}

// async global->LDS, 16B per lane. LDS dest must be wave-uniform base + lane*16.
__device__ __forceinline__ void gload16(const void* g, void* l) {
    __builtin_amdgcn_global_load_lds((as1_void*)(void*)(size_t)g, (as3_void*)l, 16, 0, 0);
}

#define SBAR() do { __builtin_amdgcn_sched_barrier(0); __builtin_amdgcn_s_barrier(); __builtin_amdgcn_sched_barrier(0); } while (0)

// ---------------------------------------------------------------------------
// Split fp32 -> (hi,lo) bf16, optionally also writing the transposed copies.
// ---------------------------------------------------------------------------
template<bool WRITE_NT>
__launch_bounds__(256)
__global__ void split_kernel(const float* __restrict__ src, int R, int C,
                             u16* __restrict__ hiNT, u16* __restrict__ loNT,
                             u16* __restrict__ hiT,  u16* __restrict__ loT)
{
    __shared__ u16 th[32][33];
    __shared__ u16 tl[32][33];
    int tx = threadIdx.x & 31;
    int ty = threadIdx.x >> 5;           // 0..7
    int c0 = blockIdx.x * 32;
    int r0 = blockIdx.y * 32;
#pragma unroll
    for (int k = 0; k < 4; ++k) {
        int r = ty + k * 8;
        float x = src[(size_t)(r0 + r) * C + c0 + tx];
        u16 h = f2bf(x);
        u16 lo = f2bf(x - bf2f(h));
        if constexpr (WRITE_NT) {
            hiNT[(size_t)(r0 + r) * C + c0 + tx] = h;
            loNT[(size_t)(r0 + r) * C + c0 + tx] = lo;
        }
        th[r][tx] = h;
        tl[r][tx] = lo;
    }
    __syncthreads();
#pragma unroll
    for (int k = 0; k < 4; ++k) {
        int cc = ty + k * 8;
        hiT[(size_t)(c0 + cc) * R + r0 + tx] = th[tx][cc];
        loT[(size_t)(c0 + cc) * R + r0 + tx] = tl[tx][cc];
    }
}

// ---------------------------------------------------------------------------
// 8-phase-style pipelined NT GEMM, split-bf16 fp32 emulation.
//   Tile 256x128, BK=32, 8 waves (4M x 2N, 64x64 per wave), 512 threads.
//   3 K-tile LDS buffers rotate; tile t+2 stages (global_load_lds w=16) into
//   the buffer last read at tile t-1 (>=2 barriers of separation => race-free).
//   4 phases per K-tile: phase m does {ds_read frags, issue 1 stage unit,
//   barrier, setprio+MFMA(row m), barrier}. Counted vmcnt(6|4) once per tile
//   at phase 3 certifies tile t+1 while tile t+2's loads stay in flight (T4).
//   NTERMS==3:  C = A0@B0^T + A0@B1^T + A1@B0^T   (proj, QK^T)
//   NTERMS==2:  C = A0@B0^T + A0@B1^T             (PV)
//   OUTMODE==0: fp32 C    OUTMODE==1: C split into (Ch,Cl) bf16
// A*: [M][K] bf16 row-major.  B*: [N][K] bf16 row-major (B^T form).
// grid = 1D, nwg = (N/128)*(M/256); ty-major XCD-swizzled (T1).
// ---------------------------------------------------------------------------
#define BK 32

template<int NTERMS, int OUTMODE>
__launch_bounds__(512)
__global__ void gemm8(const u16* __restrict__ A0, const u16* __restrict__ A1,
                      const u16* __restrict__ B0, const u16* __restrict__ B1,
                      int M, int N, int K, int NX,
                      float* __restrict__ Cf,
                      u16* __restrict__ Ch, u16* __restrict__ Cl)
{
    constexpr int OFF_A0 = 0;
    constexpr int OFF_A1 = 8192;                         // used only if NTERMS==3
    constexpr int OFF_B0 = (NTERMS == 3) ? 16384 : 8192;
    constexpr int OFF_B1 = OFF_B0 + 4096;
    constexpr int BUFSZ  = (NTERMS == 3) ? 24576 : 16384; // u16 elems per K-tile buffer
    constexpr int VMS    = (NTERMS == 3) ? 6 : 4;         // loads per tile (steady vmcnt)

    __shared__ u16 lds[3 * BUFSZ];                        // 144KB (NT3) / 96KB (NT2)

    int tid = threadIdx.x;
    int w = tid >> 6, l = tid & 63;
    int wm = w >> 1, wn = w & 1;          // wave tile: rows wm*64, cols wn*64
    int ln15 = l & 15;
    int lk8  = (l >> 4) * 8;

    // XCD-aware bijective swizzle (T1), ty-major chunking (requires nwg%8==0)
    int b = blockIdx.x, nwg = gridDim.x, L = b;
    if ((nwg & 7) == 0) { int c = nwg >> 3; L = (b & 7) * c + (b >> 3); }
    int tx = L % NX, ty = L / NX;
    int m0 = ty * 256, n0 = tx * 128;

    // staging geometry: thread t covers 16B chunk t of each 16KB unit
    int ar0 = tid >> 2;                   // 0..127
    int ac  = (tid & 3) * 8;
    const u16* pA0 = A0 + (size_t)(m0 + ar0) * K + ac;
    const u16* pA1 = (NTERMS == 3) ? A1 + (size_t)(m0 + ar0) * K + ac : nullptr;
    const u16* pB0 = B0 + (size_t)(n0 + ar0) * K + ac;
    const u16* pB1 = B1 + (size_t)(n0 + ar0) * K + ac;
    const size_t rstep = (size_t)128 * K;

    const int NT = K / BK;

    f32x4 acc[4][4];
#pragma unroll
    for (int i = 0; i < 4; ++i)
#pragma unroll
        for (int j = 0; j < 4; ++j) acc[i][j] = (f32x4){0.f, 0.f, 0.f, 0.f};

    // ---- prologue: stage tile0 -> buf0, tile1 -> buf1; certify tile0 ----
    {
        u16* b0 = lds;
        u16* b1 = lds + BUFSZ;
#pragma unroll
        for (int tt = 0; tt < 2; ++tt) {
            u16* base = tt ? b1 : b0;
            int koff = tt * BK;
            gload16(pA0 + koff,         base + OFF_A0 + tid * 8);
            gload16(pA0 + koff + rstep, base + OFF_A0 + tid * 8 + 4096);
            if constexpr (NTERMS == 3) {
                gload16(pA1 + koff,         base + OFF_A1 + tid * 8);
                gload16(pA1 + koff + rstep, base + OFF_A1 + tid * 8 + 4096);
            }
            gload16(pB0 + koff, base + OFF_B0 + tid * 8);
            gload16(pB1 + koff, base + OFF_B1 + tid * 8);
        }
        asm volatile("s_waitcnt vmcnt(%0)" :: "i"(VMS) : "memory");
        SBAR();
    }

    int rb = 0, sb = 2, kpre = 2 * BK;
    for (int t = 0; t < NT; ++t) {
        const u16* lr = lds + rb * BUFSZ;
        u16*       ls = lds + sb * BUFSZ;
        bool dostage = (t + 2 < NT);

        bf16x8 fb0[4], fb1[4];
#pragma unroll
        for (int m = 0; m < 4; ++m) {
            // --- frag ds_reads for this phase (from certified buffer lr) ---
            if (m == 0) {
#pragma unroll
                for (int n = 0; n < 4; ++n) {
                    int row = wn * 64 + n * 16 + ln15;
                    fb0[n] = *(const bf16x8*)&lr[OFF_B0 + row * BK + lk8];
                    fb1[n] = *(const bf16x8*)&lr[OFF_B1 + row * BK + lk8];
                }
            }
            int arow = wm * 64 + m * 16 + ln15;
            bf16x8 fa0 = *(const bf16x8*)&lr[OFF_A0 + arow * BK + lk8];
            bf16x8 fa1;
            if constexpr (NTERMS == 3)
                fa1 = *(const bf16x8*)&lr[OFF_A1 + arow * BK + lk8];

            // --- issue this phase's stage unit for tile t+2 -> buffer sb ---
            if (dostage) {
                if constexpr (NTERMS == 3) {
                    if (m == 0) {
                        gload16(pA0 + kpre,         ls + OFF_A0 + tid * 8);
                        gload16(pA0 + kpre + rstep, ls + OFF_A0 + tid * 8 + 4096);
                    } else if (m == 1) {
                        gload16(pA1 + kpre,         ls + OFF_A1 + tid * 8);
                        gload16(pA1 + kpre + rstep, ls + OFF_A1 + tid * 8 + 4096);
                    } else if (m == 2) {
                        gload16(pB0 + kpre, ls + OFF_B0 + tid * 8);
                        gload16(pB1 + kpre, ls + OFF_B1 + tid * 8);
                    }
                } else {
                    if (m == 0) {
                        gload16(pA0 + kpre,         ls + OFF_A0 + tid * 8);
                        gload16(pA0 + kpre + rstep, ls + OFF_A0 + tid * 8 + 4096);
                    } else if (m == 1) {
                        gload16(pB0 + kpre, ls + OFF_B0 + tid * 8);
                    } else if (m == 2) {
                        gload16(pB1 + kpre, ls + OFF_B1 + tid * 8);
                    }
                }
            }

            SBAR();                          // phase open: role-split point
            __builtin_amdgcn_s_setprio(1);
#pragma unroll
            for (int n = 0; n < 4; ++n) {
                acc[m][n] = __builtin_amdgcn_mfma_f32_16x16x32_bf16(fa0, fb0[n], acc[m][n], 0, 0, 0);
                acc[m][n] = __builtin_amdgcn_mfma_f32_16x16x32_bf16(fa0, fb1[n], acc[m][n], 0, 0, 0);
                if constexpr (NTERMS == 3)
                    acc[m][n] = __builtin_amdgcn_mfma_f32_16x16x32_bf16(fa1, fb0[n], acc[m][n], 0, 0, 0);
            }
            __builtin_amdgcn_s_setprio(0);
            if (m == 3) {
                // certify tile t+1 before next tile's ds_reads; keep t+2's
                // loads (VMS newest) in flight  (T4 counted vmcnt)
                if (dostage) asm volatile("s_waitcnt vmcnt(%0)" :: "i"(VMS) : "memory");
                else         asm volatile("s_waitcnt vmcnt(0)" ::: "memory");
            }
            SBAR();                          // phase close
        }

        kpre += BK;
        rb = (rb == 2) ? 0 : rb + 1;
        sb = (sb == 2) ? 0 : sb + 1;
    }

    // Epilogue. C/D frag mapping (verified m89): col = lane&15, row = (lane>>4)*4 + reg
    int orow = m0 + wm * 64 + (l >> 4) * 4;
    int ocol = n0 + wn * 64 + ln15;
#pragma unroll
    for (int m = 0; m < 4; ++m)
#pragma unroll
        for (int n = 0; n < 4; ++n)
#pragma unroll
            for (int q = 0; q < 4; ++q) {
                size_t idx = (size_t)(orow + m * 16 + q) * N + (ocol + n * 16);
                float v = acc[m][n][q];
                if constexpr (OUTMODE == 0) {
                    Cf[idx] = v;
                } else {
                    u16 h = f2bf(v);
                    Ch[idx] = h;
                    Cl[idx] = f2bf(v - bf2f(h));
                }
            }
}

// ---------------------------------------------------------------------------
// Row softmax: P[r][:] = softmax(S[r][:] * SM_SCALE), fp32 -> bf16
// ---------------------------------------------------------------------------
__launch_bounds__(256)
__global__ void softmax_kernel(const float* __restrict__ S, u16* __restrict__ P)
{
    size_t row = blockIdx.x;
    const f32x4* s4 = (const f32x4*)(S + row * SEQ);
    int t = threadIdx.x;
    int w = t >> 6, l = t & 63;

    float v[32];
    float mx = -3.4e38f;
#pragma unroll
    for (int i = 0; i < 8; ++i) {
        f32x4 x = s4[t + i * 256];
#pragma unroll
        for (int j = 0; j < 4; ++j) {
            float f = x[j] * SM_SCALE;
            v[i * 4 + j] = f;
            mx = fmaxf(mx, f);
        }
    }
#pragma unroll
    for (int off = 32; off; off >>= 1) mx = fmaxf(mx, __shfl_xor(mx, off));

    __shared__ float redm[4];
    __shared__ float reds[4];
    if (l == 0) redm[w] = mx;
    __syncthreads();
    mx = fmaxf(fmaxf(redm[0], redm[1]), fmaxf(redm[2], redm[3]));

    float sum = 0.f;
#pragma unroll
    for (int i = 0; i < 32; ++i) {
        v[i] = __expf(v[i] - mx);
        sum += v[i];
    }
#pragma unroll
    for (int off = 32; off; off >>= 1) sum += __shfl_xor(sum, off);
    if (l == 0) reds[w] = sum;
    __syncthreads();
    sum = reds[0] + reds[1] + reds[2] + reds[3];
    float inv = 1.f / sum;

    u16* p = P + row * SEQ;
#pragma unroll
    for (int i = 0; i < 8; ++i) {
        u16x4 o;
#pragma unroll
        for (int j = 0; j < 4; ++j) o[j] = f2bf(v[i * 4 + j] * inv);
        *(u16x4*)&p[4 * (t + i * 256)] = o;
    }
}

// ---------------------------------------------------------------------------
extern "C" void kernel_launch(void* const* d_in, const int* in_sizes, int n_in,
                              void* d_out, int out_size, void* d_ws, size_t ws_size,
                              hipStream_t stream)
{
    const float* X  = (const float*)d_in[0];
    const float* Wq = (const float*)d_in[1];
    const float* Wk = (const float*)d_in[2];
    float* out = (float*)d_out;
    char* ws = (char*)d_ws;

    const size_t XE = (size_t)SEQ * DIM;
    const size_t WE = (size_t)DIM * DIM;

    u16* Xh   = (u16*)ws;
    u16* Xl   = Xh + XE;
    u16* XhT  = Xl + XE;
    u16* XlT  = XhT + XE;
    u16* WqhT = XlT + XE;
    u16* WqlT = WqhT + WE;
    u16* WkhT = WqlT + WE;
    u16* WklT = WkhT + WE;
    u16* Qh   = WklT + WE;
    u16* Ql   = Qh + XE;
    u16* Kh   = Ql + XE;
    u16* Kl   = Kh + XE;
    char* dyn = (char*)(Kl + XE);

    size_t fixed = (size_t)(dyn - ws);
    size_t avail = ws_size > fixed ? ws_size - fixed : 0;

    // 1) splits
    split_kernel<true ><<<dim3(DIM / 32, SEQ / 32), 256, 0, stream>>>(X, SEQ, DIM, Xh, Xl, XhT, XlT);
    split_kernel<false><<<dim3(DIM / 32, DIM / 32), 256, 0, stream>>>(Wq, DIM, DIM, nullptr, nullptr, WqhT, WqlT);
    split_kernel<false><<<dim3(DIM / 32, DIM / 32), 256, 0, stream>>>(Wk, DIM, DIM, nullptr, nullptr, WkhT, WklT);

    // 2) projections: Q = X@Wq, K = X@Wk  (fp32-accurate, written as hi/lo bf16)
    {
        int nwg = (DIM / 128) * (SEQ / 256);   // 8*32 = 256
        gemm8<3, 1><<<dim3(nwg), 512, 0, stream>>>(
            Xh, Xl, WqhT, WqlT, SEQ, DIM, DIM, DIM / 128, nullptr, Qh, Ql);
        gemm8<3, 1><<<dim3(nwg), 512, 0, stream>>>(
            Xh, Xl, WkhT, WklT, SEQ, DIM, DIM, DIM / 128, nullptr, Kh, Kl);
    }

    const size_t PFULL = (size_t)SEQ * SEQ * sizeof(u16);     // 128 MB
    if (avail >= PFULL + (size_t)256 * SEQ * sizeof(float)) {
        // full-P mode: chunked QK^T+softmax into full P, then ONE PV
        u16*   Pfull = (u16*)dyn;
        float* Sbuf  = (float*)(dyn + PFULL);
        size_t srem = avail - PFULL;
        long long chll = (long long)(srem / ((size_t)SEQ * sizeof(float)));
        int CH = chll > SEQ ? SEQ : (int)chll;
        CH &= ~255;
        if (CH < 256) CH = 256;

        for (int r0 = 0; r0 < SEQ; r0 += CH) {
            int ch = (SEQ - r0 < CH) ? (SEQ - r0) : CH;
            int nwg = (SEQ / 128) * (ch / 256);
            gemm8<3, 0><<<dim3(nwg), 512, 0, stream>>>(
                Qh + (size_t)r0 * DIM, Ql + (size_t)r0 * DIM, Kh, Kl,
                ch, SEQ, DIM, SEQ / 128, Sbuf, nullptr, nullptr);
            softmax_kernel<<<ch, 256, 0, stream>>>(Sbuf, Pfull + (size_t)r0 * SEQ);
        }
        int nwg = (DIM / 128) * (SEQ / 256);
        gemm8<2, 0><<<dim3(nwg), 512, 0, stream>>>(
            Pfull, nullptr, XhT, XlT, SEQ, DIM, SEQ, DIM / 128, out, nullptr, nullptr);
    } else {
        // legacy chunked mode (small workspace)
        size_t perrow = (size_t)SEQ * 6;       // 4B S + 2B P per row
        long long chll = (long long)(avail / perrow);
        int CH = chll > SEQ ? SEQ : (int)chll;
        CH &= ~255;
        if (CH < 256) CH = 256;

        float* Sbuf = (float*)dyn;
        u16*   Pbuf = (u16*)(dyn + (size_t)CH * SEQ * sizeof(float));

        for (int r0 = 0; r0 < SEQ; r0 += CH) {
            int ch = (SEQ - r0 < CH) ? (SEQ - r0) : CH;
            int nwgq = (SEQ / 128) * (ch / 256);
            gemm8<3, 0><<<dim3(nwgq), 512, 0, stream>>>(
                Qh + (size_t)r0 * DIM, Ql + (size_t)r0 * DIM, Kh, Kl,
                ch, SEQ, DIM, SEQ / 128, Sbuf, nullptr, nullptr);
            softmax_kernel<<<ch, 256, 0, stream>>>(Sbuf, Pbuf);
            int nwgp = (DIM / 128) * (ch / 256);
            gemm8<2, 0><<<dim3(nwgp), 512, 0, stream>>>(
                Pbuf, nullptr, XhT, XlT,
                ch, DIM, SEQ, DIM / 128, out + (size_t)r0 * DIM, nullptr, nullptr);
        }
    }
}

// Round 5
// 1184.444 us; speedup vs baseline: 1.4259x; 1.4259x over previous
//
#include <hip/hip_runtime.h>

#define SEQ 8192
#define DIM 1024
#define SM_SCALE 0.03125f   // 1/sqrt(1024)
#define BK 32

typedef unsigned short u16;
typedef float f32x4 __attribute__((ext_vector_type(4)));
typedef short bf16x8 __attribute__((ext_vector_type(8)));
typedef u16   u16x4 __attribute__((ext_vector_type(4)));

typedef __attribute__((address_space(1))) void as1_void;
typedef __attribute__((address_space(3))) void as3_void;

__device__ __forceinline__ u16 f2bf(float x) {
    unsigned u = __float_as_uint(x);
    u += 0x7fffu + ((u >> 16) & 1u);           // round-to-nearest-even
    return (u16)(u >> 16);
}
__device__ __forceinline__ float bf2f(u16 b) {
    return __uint_as_float(((unsigned)b) << 16);
}

// async global->LDS, 16B per lane. LDS dest must be wave-uniform base + lane*16.
__device__ __forceinline__ void gload16(const void* g, void* l) {
    __builtin_amdgcn_global_load_lds((as1_void*)(void*)(size_t)g, (as3_void*)l, 16, 0, 0);
}

#define SBAR() do { __builtin_amdgcn_sched_barrier(0); __builtin_amdgcn_s_barrier(); __builtin_amdgcn_sched_barrier(0); } while (0)

// ---------------------------------------------------------------------------
// Split fp32 -> (hi,lo) bf16, optionally also writing the transposed copies.
// ---------------------------------------------------------------------------
template<bool WRITE_NT>
__launch_bounds__(256)
__global__ void split_kernel(const float* __restrict__ src, int R, int C,
                             u16* __restrict__ hiNT, u16* __restrict__ loNT,
                             u16* __restrict__ hiT,  u16* __restrict__ loT)
{
    __shared__ u16 th[32][33];
    __shared__ u16 tl[32][33];
    int tx = threadIdx.x & 31;
    int ty = threadIdx.x >> 5;           // 0..7
    int c0 = blockIdx.x * 32;
    int r0 = blockIdx.y * 32;
#pragma unroll
    for (int k = 0; k < 4; ++k) {
        int r = ty + k * 8;
        float x = src[(size_t)(r0 + r) * C + c0 + tx];
        u16 h = f2bf(x);
        u16 lo = f2bf(x - bf2f(h));
        if constexpr (WRITE_NT) {
            hiNT[(size_t)(r0 + r) * C + c0 + tx] = h;
            loNT[(size_t)(r0 + r) * C + c0 + tx] = lo;
        }
        th[r][tx] = h;
        tl[r][tx] = lo;
    }
    __syncthreads();
#pragma unroll
    for (int k = 0; k < 4; ++k) {
        int cc = ty + k * 8;
        hiT[(size_t)(c0 + cc) * R + r0 + tx] = th[tx][cc];
        loT[(size_t)(c0 + cc) * R + r0 + tx] = tl[tx][cc];
    }
}

__launch_bounds__(256)
__global__ void zero_kernel(float* __restrict__ p, int n4)
{
    int i = blockIdx.x * 256 + threadIdx.x;
    int stride = gridDim.x * 256;
    for (; i < n4; i += stride) ((f32x4*)p)[i] = (f32x4){0.f, 0.f, 0.f, 0.f};
}

// ---------------------------------------------------------------------------
// Double-buffered NT GEMM, split-bf16 fp32 emulation. 8 waves (2M x 4N).
//   - global_load_lds w=16 into linear LDS; source pre-swizzled (G21) so
//     ds_read_b128 at stride-64B rows is bank-conflict-free (cb ^= (row>>1)&3)
//   - all of tile t+1's stages issued at START of tile t's compute
//     (~full tile of latency cover); ONE vmcnt(0)+barrier per K-tile
//   - XCD decode: x = b&7; within XCD, supertiles of TXS x GY blocks are
//     co-resident -> B-panel set stays L2-resident, A-panels shared
//   NTERMS==3: C = A0B0^T + A0B1^T + A1B0^T   NTERMS==2: C = A0B0^T + A0B1^T
//   OUTMODE: 0 = fp32 store, 1 = split hi/lo bf16 store, 2 = fp32 atomicAdd
// ---------------------------------------------------------------------------
template<int BM, int BN, int NTERMS, int OUTMODE>
__launch_bounds__(512)
__global__ void gemmX(const u16* __restrict__ A0, const u16* __restrict__ A1,
                      const u16* __restrict__ B0, const u16* __restrict__ B1,
                      int M, int N, int K, int TXS, int GY, int NKS,
                      float* __restrict__ Cf,
                      u16* __restrict__ Ch, u16* __restrict__ Cl)
{
    constexpr int WR = BM / 2, WC = BN / 4;       // per-wave output tile
    constexpr int MFR = WR / 16, NFR = WC / 16;   // frags per wave
    constexpr int NA = (NTERMS == 3) ? 2 : 1;
    constexpr int EA = BM * BK, EB = BN * BK;     // elems per tensor tile
    constexpr int OFF_B0 = NA * EA;
    constexpr int OFF_B1 = NA * EA + EB;
    constexpr int BUFSZ = NA * EA + 2 * EB;       // elems per K-tile buffer
    constexpr int NCH = BUFSZ / 8 / 512;          // 16B chunks per thread

    __shared__ u16 lds[2 * BUFSZ];

    int tid = threadIdx.x;
    int w = tid >> 6, l = tid & 63;
    int wm = w >> 2, wn = w & 3;                  // 2 x 4 wave grid
    int ln15 = l & 15;
    int kb = l >> 4;                              // k-block of this lane (0..3)

    // ---- XCD-aware block decode ----
    int b = blockIdx.x;
    int x = b & 7, j = b >> 3;
    int span = TXS * GY;
    int g = j / span, r = j % span;
    int cx = x * TXS + (r % TXS);
    int ty = g * GY + (r / TXS);
    int tx = cx / NKS, ks = cx % NKS;
    int m0 = ty * BM, n0 = tx * BN;
    int kbase = ks * (K / NKS);
    const int NT = (K / NKS) / BK;

    // ---- per-thread staging chunk pointers (source pre-swizzled) ----
    const u16* gp[NCH];
    int lof[NCH];
#pragma unroll
    for (int i = 0; i < NCH; ++i) {
        int c = tid + i * 512;
        const u16* bp;
        int cc;
        if (c < BM * 4) {
            cc = c;
            bp = A0 + (size_t)(m0 + (cc >> 2)) * K;
        } else if (NA == 2 && c < 2 * BM * 4) {
            cc = c - BM * 4;
            bp = A1 + (size_t)(m0 + (cc >> 2)) * K;
        } else {
            int c2 = c - NA * BM * 4;
            if (c2 < BN * 4) {
                cc = c2;
                bp = B0 + (size_t)(n0 + (cc >> 2)) * K;
            } else {
                cc = c2 - BN * 4;
                bp = B1 + (size_t)(n0 + (cc >> 2)) * K;
            }
        }
        int row = cc >> 2;
        int cb = (cc & 3) ^ ((row >> 1) & 3);     // inverse swizzle on source
        gp[i] = bp + kbase + cb * 8;
        lof[i] = c * 8;                           // linear LDS dest (elems)
    }

    f32x4 acc[MFR][NFR];
#pragma unroll
    for (int i = 0; i < MFR; ++i)
#pragma unroll
        for (int jn = 0; jn < NFR; ++jn) acc[i][jn] = (f32x4){0.f, 0.f, 0.f, 0.f};

    // ---- prologue: stage tile 0 -> buf0 ----
#pragma unroll
    for (int i = 0; i < NCH; ++i) gload16(gp[i], lds + lof[i]);
    asm volatile("s_waitcnt vmcnt(0)" ::: "memory");
    SBAR();

    int kof = BK;
    for (int t = 0; t < NT; ++t) {
        const u16* cur = lds + (t & 1) * BUFSZ;
        u16* nxt = lds + ((t + 1) & 1) * BUFSZ;

        // issue ALL of tile t+1's stages now (max latency cover)
        if (t + 1 < NT) {
#pragma unroll
            for (int i = 0; i < NCH; ++i) gload16(gp[i] + kof, nxt + lof[i]);
        }
        __builtin_amdgcn_sched_barrier(0);        // pin stages early

        // B fragments (held across all MFR phases)
        bf16x8 fb0[NFR], fb1[NFR];
#pragma unroll
        for (int n = 0; n < NFR; ++n) {
            int rr = wn * WC + n * 16 + ln15;
            int sw = (kb ^ ((rr >> 1) & 3)) << 3;
            fb0[n] = *(const bf16x8*)&cur[OFF_B0 + rr * BK + sw];
            fb1[n] = *(const bf16x8*)&cur[OFF_B1 + rr * BK + sw];
        }

#pragma unroll
        for (int p = 0; p < MFR; ++p) {
            int rr = wm * WR + p * 16 + ln15;
            int sw = (kb ^ ((rr >> 1) & 3)) << 3;
            bf16x8 fa0 = *(const bf16x8*)&cur[rr * BK + sw];
            bf16x8 fa1;
            if constexpr (NA == 2)
                fa1 = *(const bf16x8*)&cur[EA + rr * BK + sw];

            __builtin_amdgcn_s_setprio(1);
#pragma unroll
            for (int n = 0; n < NFR; ++n) {
                acc[p][n] = __builtin_amdgcn_mfma_f32_16x16x32_bf16(fa0, fb0[n], acc[p][n], 0, 0, 0);
                acc[p][n] = __builtin_amdgcn_mfma_f32_16x16x32_bf16(fa0, fb1[n], acc[p][n], 0, 0, 0);
                if constexpr (NA == 2)
                    acc[p][n] = __builtin_amdgcn_mfma_f32_16x16x32_bf16(fa1, fb0[n], acc[p][n], 0, 0, 0);
            }
            __builtin_amdgcn_s_setprio(0);
        }

        kof += BK;
        asm volatile("s_waitcnt vmcnt(0)" ::: "memory");  // t+1's stages done
        SBAR();                                           // all reads of cur done
    }

    // ---- epilogue. C/D frag map (m89): col = lane&15, row = (lane>>4)*4+q ----
    int orow = m0 + wm * WR + (l >> 4) * 4;
    int ocol = n0 + wn * WC + ln15;
#pragma unroll
    for (int m = 0; m < MFR; ++m)
#pragma unroll
        for (int n = 0; n < NFR; ++n)
#pragma unroll
            for (int q = 0; q < 4; ++q) {
                size_t idx = (size_t)(orow + m * 16 + q) * N + (ocol + n * 16);
                float v = acc[m][n][q];
                if constexpr (OUTMODE == 0) {
                    Cf[idx] = v;
                } else if constexpr (OUTMODE == 1) {
                    u16 h = f2bf(v);
                    Ch[idx] = h;
                    Cl[idx] = f2bf(v - bf2f(h));
                } else {
                    atomicAdd(&Cf[idx], v);
                }
            }
}

// ---------------------------------------------------------------------------
// Row softmax: P[r][:] = softmax(S[r][:] * SM_SCALE), fp32 -> bf16
// ---------------------------------------------------------------------------
__launch_bounds__(256)
__global__ void softmax_kernel(const float* __restrict__ S, u16* __restrict__ P)
{
    size_t row = blockIdx.x;
    const f32x4* s4 = (const f32x4*)(S + row * SEQ);
    int t = threadIdx.x;
    int w = t >> 6, l = t & 63;

    float v[32];
    float mx = -3.4e38f;
#pragma unroll
    for (int i = 0; i < 8; ++i) {
        f32x4 xv = s4[t + i * 256];
#pragma unroll
        for (int jj = 0; jj < 4; ++jj) {
            float f = xv[jj] * SM_SCALE;
            v[i * 4 + jj] = f;
            mx = fmaxf(mx, f);
        }
    }
#pragma unroll
    for (int off = 32; off; off >>= 1) mx = fmaxf(mx, __shfl_xor(mx, off));

    __shared__ float redm[4];
    __shared__ float reds[4];
    if (l == 0) redm[w] = mx;
    __syncthreads();
    mx = fmaxf(fmaxf(redm[0], redm[1]), fmaxf(redm[2], redm[3]));

    float sum = 0.f;
#pragma unroll
    for (int i = 0; i < 32; ++i) {
        v[i] = __expf(v[i] - mx);
        sum += v[i];
    }
#pragma unroll
    for (int off = 32; off; off >>= 1) sum += __shfl_xor(sum, off);
    if (l == 0) reds[w] = sum;
    __syncthreads();
    sum = reds[0] + reds[1] + reds[2] + reds[3];
    float inv = 1.f / sum;

    u16* p = P + row * SEQ;
#pragma unroll
    for (int i = 0; i < 8; ++i) {
        u16x4 o;
#pragma unroll
        for (int jj = 0; jj < 4; ++jj) o[jj] = f2bf(v[i * 4 + jj] * inv);
        *(u16x4*)&p[4 * (t + i * 256)] = o;
    }
}

// ---------------------------------------------------------------------------
extern "C" void kernel_launch(void* const* d_in, const int* in_sizes, int n_in,
                              void* d_out, int out_size, void* d_ws, size_t ws_size,
                              hipStream_t stream)
{
    const float* X  = (const float*)d_in[0];
    const float* Wq = (const float*)d_in[1];
    const float* Wk = (const float*)d_in[2];
    float* out = (float*)d_out;
    char* ws = (char*)d_ws;

    const size_t XE = (size_t)SEQ * DIM;
    const size_t WE = (size_t)DIM * DIM;

    u16* Xh   = (u16*)ws;
    u16* Xl   = Xh + XE;
    u16* XhT  = Xl + XE;
    u16* XlT  = XhT + XE;
    u16* WqhT = XlT + XE;
    u16* WqlT = WqhT + WE;
    u16* WkhT = WqlT + WE;
    u16* WklT = WkhT + WE;
    u16* Qh   = WklT + WE;
    u16* Ql   = Qh + XE;
    u16* Kh   = Ql + XE;
    u16* Kl   = Kh + XE;
    char* dyn = (char*)(Kl + XE);

    size_t fixed = (size_t)(dyn - ws);
    size_t avail = ws_size > fixed ? ws_size - fixed : 0;

    // chunk rows: S fp32 (32KB/row) + P bf16 (16KB/row)
    size_t perrow = (size_t)SEQ * 6;
    long long chll = (long long)(avail / perrow);
    int CH = chll > SEQ ? SEQ : (int)chll;
    CH &= ~255;
    if (CH < 256) CH = 256;

    float* Sbuf = (float*)dyn;
    u16*   Pbuf = (u16*)(dyn + (size_t)CH * SEQ * sizeof(float));

    // 1) splits
    split_kernel<true ><<<dim3(DIM / 32, SEQ / 32), 256, 0, stream>>>(X, SEQ, DIM, Xh, Xl, XhT, XlT);
    split_kernel<false><<<dim3(DIM / 32, DIM / 32), 256, 0, stream>>>(Wq, DIM, DIM, nullptr, nullptr, WqhT, WqlT);
    split_kernel<false><<<dim3(DIM / 32, DIM / 32), 256, 0, stream>>>(Wk, DIM, DIM, nullptr, nullptr, WkhT, WklT);

    // 2) projections: Q = X@Wq, K = X@Wk (fp32-accurate hi/lo bf16 out)
    //    tile 256x128, grid 8tx*32ty=256, XCD owns 1 tx column (W-set L2-res)
    gemmX<256, 128, 3, 1><<<dim3(256), 512, 0, stream>>>(
        Xh, Xl, WqhT, WqlT, SEQ, DIM, DIM, 1, 32, 1, nullptr, Qh, Ql);
    gemmX<256, 128, 3, 1><<<dim3(256), 512, 0, stream>>>(
        Xh, Xl, WkhT, WklT, SEQ, DIM, DIM, 1, 32, 1, nullptr, Kh, Kl);

    // 3) zero the output (PV accumulates via atomicAdd)
    zero_kernel<<<dim3(512), 256, 0, stream>>>(out, (int)(XE / 4));

    // 4) chunked: S = Q K^T ; P = softmax ; out += P X (split-K=4)
    for (int r0 = 0; r0 < SEQ; r0 += CH) {
        int ch = (SEQ - r0 < CH) ? (SEQ - r0) : CH;
        int nty = ch / 256;

        // QK^T: tile 256x256, CXN=32 (tx), TXS=4, GY=8
        gemmX<256, 256, 3, 0><<<dim3(32 * nty), 512, 0, stream>>>(
            Qh + (size_t)r0 * DIM, Ql + (size_t)r0 * DIM, Kh, Kl,
            ch, SEQ, DIM, 4, 8, 1, Sbuf, nullptr, nullptr);

        softmax_kernel<<<ch, 256, 0, stream>>>(Sbuf, Pbuf);

        // PV: out += P @ X^T. tile 256x128, split-K=4 -> CXN = 8tx*4ks = 32,
        // TXS=4 => XCD x owns tx=x (X^T panel 4MB L2-resident), all ks
        gemmX<256, 128, 2, 2><<<dim3(32 * nty), 512, 0, stream>>>(
            Pbuf, nullptr, XhT, XlT,
            ch, DIM, SEQ, 4, 8, 4, out + (size_t)r0 * DIM, nullptr, nullptr);
    }
}

// Round 7
// 947.005 us; speedup vs baseline: 1.7834x; 1.2507x over previous
//
#include <hip/hip_runtime.h>

#define SEQ 8192
#define DIM 1024
#define SM_SCALE 0.03125f   // 1/sqrt(1024)
#define BK 32

typedef unsigned short u16;
typedef float f32x4 __attribute__((ext_vector_type(4)));
typedef short bf16x8 __attribute__((ext_vector_type(8)));
typedef u16   u16x4 __attribute__((ext_vector_type(4)));

typedef __attribute__((address_space(1))) void as1_void;
typedef __attribute__((address_space(3))) void as3_void;

__device__ __forceinline__ u16 f2bf(float x) {
    unsigned u = __float_as_uint(x);
    u += 0x7fffu + ((u >> 16) & 1u);           // round-to-nearest-even
    return (u16)(u >> 16);
}
__device__ __forceinline__ float bf2f(u16 b) {
    return __uint_as_float(((unsigned)b) << 16);
}

// async global->LDS, 16B per lane. LDS dest must be wave-uniform base + lane*16.
__device__ __forceinline__ void gload16(const void* g, void* l) {
    __builtin_amdgcn_global_load_lds((as1_void*)(void*)(size_t)g, (as3_void*)l, 16, 0, 0);
}

#define SBAR() do { __builtin_amdgcn_sched_barrier(0); __builtin_amdgcn_s_barrier(); __builtin_amdgcn_sched_barrier(0); } while (0)
#define VWAIT(n) do { asm volatile("s_waitcnt vmcnt(%0)" :: "i"(n) : "memory"); __builtin_amdgcn_sched_barrier(0); } while (0)

// ---------------------------------------------------------------------------
// Split fp32 -> (hi,lo) bf16, optionally also writing the transposed copies.
// ---------------------------------------------------------------------------
template<bool WRITE_NT>
__launch_bounds__(256)
__global__ void split_kernel(const float* __restrict__ src, int R, int C,
                             u16* __restrict__ hiNT, u16* __restrict__ loNT,
                             u16* __restrict__ hiT,  u16* __restrict__ loT)
{
    __shared__ u16 th[32][33];
    __shared__ u16 tl[32][33];
    int tx = threadIdx.x & 31;
    int ty = threadIdx.x >> 5;           // 0..7
    int c0 = blockIdx.x * 32;
    int r0 = blockIdx.y * 32;
#pragma unroll
    for (int k = 0; k < 4; ++k) {
        int r = ty + k * 8;
        float x = src[(size_t)(r0 + r) * C + c0 + tx];
        u16 h = f2bf(x);
        u16 lo = f2bf(x - bf2f(h));
        if constexpr (WRITE_NT) {
            hiNT[(size_t)(r0 + r) * C + c0 + tx] = h;
            loNT[(size_t)(r0 + r) * C + c0 + tx] = lo;
        }
        th[r][tx] = h;
        tl[r][tx] = lo;
    }
    __syncthreads();
#pragma unroll
    for (int k = 0; k < 4; ++k) {
        int cc = ty + k * 8;
        hiT[(size_t)(c0 + cc) * R + r0 + tx] = th[tx][cc];
        loT[(size_t)(c0 + cc) * R + r0 + tx] = tl[tx][cc];
    }
}

__launch_bounds__(256)
__global__ void zero_kernel(float* __restrict__ p, int n4)
{
    int i = blockIdx.x * 256 + threadIdx.x;
    int stride = gridDim.x * 256;
    for (; i < n4; i += stride) ((f32x4*)p)[i] = (f32x4){0.f, 0.f, 0.f, 0.f};
}

// ---------------------------------------------------------------------------
// Counted-vmcnt double-buffered NT GEMM, split-bf16 fp32 emulation. 8 waves.
//   Staging chunks split into B-group (GB/thread, oldest) and A-group (GA).
//   Per tile t: [issue B(t+1)] [fb ds_reads] [vmcnt(GB): A(t) certified]
//   [barrier] [8 MFMA phases; issue A(t+1) at p=4] [vmcnt(GA): B(t+1)
//   certified] [barrier].  Loads never drain to 0 in steady state (T4).
//   Source pre-swizzled (G21) -> conflict-free ds_read_b128.
//   XCD decode: x = b&7; TXS x GY supertiles co-resident per XCD (T1).
//   NTERMS==3: C = A0B0^T + A0B1^T + A1B0^T   NTERMS==2: C = A0B0^T + A0B1^T
//   OUTMODE: 0 = fp32 store, 1 = split hi/lo bf16 store, 2 = fp32 atomicAdd
// ---------------------------------------------------------------------------
template<int BM, int BN, int NTERMS, int OUTMODE>
__launch_bounds__(512)
__global__ void gemmX(const u16* __restrict__ A0, const u16* __restrict__ A1,
                      const u16* __restrict__ B0, const u16* __restrict__ B1,
                      int M, int N, int K, int TXS, int GY, int NKS,
                      float* __restrict__ Cf,
                      u16* __restrict__ Ch, u16* __restrict__ Cl)
{
    constexpr int WR = BM / 2, WC = BN / 4;       // per-wave output tile
    constexpr int MFR = WR / 16, NFR = WC / 16;   // frags per wave
    constexpr int NA = (NTERMS == 3) ? 2 : 1;
    constexpr int EA = BM * BK, EB = BN * BK;     // elems per tensor tile
    constexpr int OFF_B0 = NA * EA;
    constexpr int BUFSZ = NA * EA + 2 * EB;       // elems per K-tile buffer
    constexpr int GA = NA * BM * 4 / 512;         // A 16B-chunks per thread
    constexpr int GB = 2 * BN * 4 / 512;          // B 16B-chunks per thread

    __shared__ u16 lds[2 * BUFSZ];

    int tid = threadIdx.x;
    int w = tid >> 6, l = tid & 63;
    int wm = w >> 2, wn = w & 3;                  // 2 x 4 wave grid
    int ln15 = l & 15;
    int kb = l >> 4;                              // k-block of this lane (0..3)

    // ---- XCD-aware block decode ----
    int b = blockIdx.x;
    int x = b & 7, j = b >> 3;
    int span = TXS * GY;
    int g = j / span, r = j % span;
    int cx = x * TXS + (r % TXS);
    int ty = g * GY + (r / TXS);
    int tx = cx / NKS, ks = cx % NKS;
    int m0 = ty * BM, n0 = tx * BN;
    int kbase = ks * (K / NKS);
    const int NT = (K / NKS) / BK;

    // ---- per-thread staging chunk pointers (source pre-swizzled, G21) ----
    const u16* gpA[GA]; int lofA[GA];
#pragma unroll
    for (int i = 0; i < GA; ++i) {
        int c = tid + i * 512;
        const u16* bp; int cc;
        if (NA == 1 || c < BM * 4) { cc = c;          bp = A0 + (size_t)(m0 + (cc >> 2)) * K; }
        else                       { cc = c - BM * 4; bp = A1 + (size_t)(m0 + (cc >> 2)) * K; }
        int row = cc >> 2;
        int cb = (cc & 3) ^ ((row >> 1) & 3);
        gpA[i] = bp + kbase + cb * 8;
        lofA[i] = c * 8;
    }
    const u16* gpB[GB]; int lofB[GB];
#pragma unroll
    for (int i = 0; i < GB; ++i) {
        int c = tid + i * 512;
        const u16* bp; int cc;
        if (c < BN * 4) { cc = c;          bp = B0 + (size_t)(n0 + (cc >> 2)) * K; }
        else            { cc = c - BN * 4; bp = B1 + (size_t)(n0 + (cc >> 2)) * K; }
        int row = cc >> 2;
        int cb = (cc & 3) ^ ((row >> 1) & 3);
        gpB[i] = bp + kbase + cb * 8;
        lofB[i] = OFF_B0 + c * 8;
    }

    f32x4 acc[MFR][NFR];
#pragma unroll
    for (int i = 0; i < MFR; ++i)
#pragma unroll
        for (int jn = 0; jn < NFR; ++jn) acc[i][jn] = (f32x4){0.f, 0.f, 0.f, 0.f};

    // ---- prologue: stage tile0 (B first, then A); certify B, keep A in flight
#pragma unroll
    for (int i = 0; i < GB; ++i) gload16(gpB[i], lds + lofB[i]);
#pragma unroll
    for (int i = 0; i < GA; ++i) gload16(gpA[i], lds + lofA[i]);
    VWAIT(GA);                    // B(0) done; A(0) (GA chunks) outstanding
    SBAR();

    int kof = BK;
    for (int t = 0; t < NT; ++t) {
        const u16* cur = lds + (t & 1) * BUFSZ;
        u16* nxt = lds + ((t + 1) & 1) * BUFSZ;
        bool pre = (t + 1 < NT);

        // issue B(t+1) early (oldest of next tile's loads)
        if (pre) {
#pragma unroll
            for (int i = 0; i < GB; ++i) gload16(gpB[i] + kof, nxt + lofB[i]);
        }

        // B fragments of tile t (region certified at end of tile t-1)
        bf16x8 fb0[NFR], fb1[NFR];
#pragma unroll
        for (int n = 0; n < NFR; ++n) {
            int rr = wn * WC + n * 16 + ln15;
            int sw = (kb ^ ((rr >> 1) & 3)) << 3;
            fb0[n] = *(const bf16x8*)&cur[OFF_B0 + rr * BK + sw];
            fb1[n] = *(const bf16x8*)&cur[OFF_B0 + EB + rr * BK + sw];
        }

        // certify A(t): leave exactly B(t+1)'s GB chunks in flight
        if (pre) VWAIT(GB); else VWAIT(0);
        SBAR();

#pragma unroll
        for (int p = 0; p < MFR; ++p) {
            int rr = wm * WR + p * 16 + ln15;
            int sw = (kb ^ ((rr >> 1) & 3)) << 3;
            bf16x8 fa0 = *(const bf16x8*)&cur[rr * BK + sw];
            bf16x8 fa1;
            if constexpr (NA == 2)
                fa1 = *(const bf16x8*)&cur[EA + rr * BK + sw];

            if (p == MFR / 2 && pre) {     // issue A(t+1) mid-compute
#pragma unroll
                for (int i = 0; i < GA; ++i) gload16(gpA[i] + kof, nxt + lofA[i]);
            }

            __builtin_amdgcn_s_setprio(1);
#pragma unroll
            for (int n = 0; n < NFR; ++n) {
                acc[p][n] = __builtin_amdgcn_mfma_f32_16x16x32_bf16(fa0, fb0[n], acc[p][n], 0, 0, 0);
                acc[p][n] = __builtin_amdgcn_mfma_f32_16x16x32_bf16(fa0, fb1[n], acc[p][n], 0, 0, 0);
                if constexpr (NA == 2)
                    acc[p][n] = __builtin_amdgcn_mfma_f32_16x16x32_bf16(fa1, fb0[n], acc[p][n], 0, 0, 0);
            }
            __builtin_amdgcn_s_setprio(0);
        }

        // certify B(t+1): leave exactly A(t+1)'s GA chunks in flight
        if (pre) VWAIT(GA); else VWAIT(0);
        SBAR();
        kof += BK;
    }

    // ---- epilogue. C/D frag map (m89): col = lane&15, row = (lane>>4)*4+q ----
    int orow = m0 + wm * WR + (l >> 4) * 4;
    int ocol = n0 + wn * WC + ln15;
#pragma unroll
    for (int m = 0; m < MFR; ++m)
#pragma unroll
        for (int n = 0; n < NFR; ++n)
#pragma unroll
            for (int q = 0; q < 4; ++q) {
                size_t idx = (size_t)(orow + m * 16 + q) * N + (ocol + n * 16);
                float v = acc[m][n][q];
                if constexpr (OUTMODE == 0) {
                    Cf[idx] = v;
                } else if constexpr (OUTMODE == 1) {
                    u16 h = f2bf(v);
                    Ch[idx] = h;
                    Cl[idx] = f2bf(v - bf2f(h));
                } else {
                    atomicAdd(&Cf[idx], v);
                }
            }
}

// ---------------------------------------------------------------------------
// Row softmax: P[r][:] = softmax(S[r][:] * SM_SCALE), fp32 -> bf16
// ---------------------------------------------------------------------------
__launch_bounds__(256)
__global__ void softmax_kernel(const float* __restrict__ S, u16* __restrict__ P)
{
    size_t row = blockIdx.x;
    const f32x4* s4 = (const f32x4*)(S + row * SEQ);
    int t = threadIdx.x;
    int w = t >> 6, l = t & 63;

    float v[32];
    float mx = -3.4e38f;
#pragma unroll
    for (int i = 0; i < 8; ++i) {
        f32x4 xv = s4[t + i * 256];
#pragma unroll
        for (int jj = 0; jj < 4; ++jj) {
            float f = xv[jj] * SM_SCALE;
            v[i * 4 + jj] = f;
            mx = fmaxf(mx, f);
        }
    }
#pragma unroll
    for (int off = 32; off; off >>= 1) mx = fmaxf(mx, __shfl_xor(mx, off));

    __shared__ float redm[4];
    __shared__ float reds[4];
    if (l == 0) redm[w] = mx;
    __syncthreads();
    mx = fmaxf(fmaxf(redm[0], redm[1]), fmaxf(redm[2], redm[3]));

    float sum = 0.f;
#pragma unroll
    for (int i = 0; i < 32; ++i) {
        v[i] = __expf(v[i] - mx);
        sum += v[i];
    }
#pragma unroll
    for (int off = 32; off; off >>= 1) sum += __shfl_xor(sum, off);
    if (l == 0) reds[w] = sum;
    __syncthreads();
    sum = reds[0] + reds[1] + reds[2] + reds[3];
    float inv = 1.f / sum;

    u16* p = P + row * SEQ;
#pragma unroll
    for (int i = 0; i < 8; ++i) {
        u16x4 o;
#pragma unroll
        for (int jj = 0; jj < 4; ++jj) o[jj] = f2bf(v[i * 4 + jj] * inv);
        *(u16x4*)&p[4 * (t + i * 256)] = o;
    }
}

// ---------------------------------------------------------------------------
extern "C" void kernel_launch(void* const* d_in, const int* in_sizes, int n_in,
                              void* d_out, int out_size, void* d_ws, size_t ws_size,
                              hipStream_t stream)
{
    const float* X  = (const float*)d_in[0];
    const float* Wq = (const float*)d_in[1];
    const float* Wk = (const float*)d_in[2];
    float* out = (float*)d_out;
    char* ws = (char*)d_ws;

    const size_t XE = (size_t)SEQ * DIM;
    const size_t WE = (size_t)DIM * DIM;

    u16* Xh   = (u16*)ws;
    u16* Xl   = Xh + XE;
    u16* XhT  = Xl + XE;
    u16* XlT  = XhT + XE;
    u16* WqhT = XlT + XE;
    u16* WqlT = WqhT + WE;
    u16* WkhT = WqlT + WE;
    u16* WklT = WkhT + WE;
    u16* Qh   = WklT + WE;
    u16* Ql   = Qh + XE;
    u16* Kh   = Ql + XE;
    u16* Kl   = Kh + XE;
    char* dyn = (char*)(Kl + XE);

    size_t fixed = (size_t)(dyn - ws);
    size_t avail = ws_size > fixed ? ws_size - fixed : 0;

    // chunk rows: S fp32 (32KB/row) + P bf16 (16KB/row).
    // CH = 2048 -> QK/PV grids are exactly 256 blocks = 1 block/CU, 1 round.
    size_t perrow = (size_t)SEQ * 6;
    long long chll = (long long)(avail / perrow);
    int CH = chll > SEQ ? SEQ : (int)chll;
    if (CH >= 2048) CH = 2048;
    else { CH &= ~255; if (CH < 256) CH = 256; }

    float* Sbuf = (float*)dyn;
    u16*   Pbuf = (u16*)(dyn + (size_t)CH * SEQ * sizeof(float));

    // 1) splits
    split_kernel<true ><<<dim3(DIM / 32, SEQ / 32), 256, 0, stream>>>(X, SEQ, DIM, Xh, Xl, XhT, XlT);
    split_kernel<false><<<dim3(DIM / 32, DIM / 32), 256, 0, stream>>>(Wq, DIM, DIM, nullptr, nullptr, WqhT, WqlT);
    split_kernel<false><<<dim3(DIM / 32, DIM / 32), 256, 0, stream>>>(Wk, DIM, DIM, nullptr, nullptr, WkhT, WklT);

    // 2) projections: Q = X@Wq, K = X@Wk (fp32-accurate hi/lo bf16 out)
    //    tile 256x128, grid 8tx*32ty=256, XCD owns 1 tx column (W-set L2-res)
    gemmX<256, 128, 3, 1><<<dim3(256), 512, 0, stream>>>(
        Xh, Xl, WqhT, WqlT, SEQ, DIM, DIM, 1, 32, 1, nullptr, Qh, Ql);
    gemmX<256, 128, 3, 1><<<dim3(256), 512, 0, stream>>>(
        Xh, Xl, WkhT, WklT, SEQ, DIM, DIM, 1, 32, 1, nullptr, Kh, Kl);

    // 3) zero the output (PV accumulates via atomicAdd)
    zero_kernel<<<dim3(512), 256, 0, stream>>>(out, (int)(XE / 4));

    // 4) chunked: S = Q K^T ; P = softmax ; out += P X (split-K=4)
    for (int r0 = 0; r0 < SEQ; r0 += CH) {
        int ch = (SEQ - r0 < CH) ? (SEQ - r0) : CH;
        int nty = ch / 256;

        // QK^T: tile 256x256, TXS=4, GY=8 -> grid 256 at CH=2048
        gemmX<256, 256, 3, 0><<<dim3(32 * nty), 512, 0, stream>>>(
            Qh + (size_t)r0 * DIM, Ql + (size_t)r0 * DIM, Kh, Kl,
            ch, SEQ, DIM, 4, 8, 1, Sbuf, nullptr, nullptr);

        softmax_kernel<<<ch, 256, 0, stream>>>(Sbuf, Pbuf);

        // PV: out += P @ X^T. tile 256x128, split-K=4; XCD x owns tx=x
        // (X^T panel 4MB L2-resident), all ks
        gemmX<256, 128, 2, 2><<<dim3(32 * nty), 512, 0, stream>>>(
            Pbuf, nullptr, XhT, XlT,
            ch, DIM, SEQ, 4, 8, 4, out + (size_t)r0 * DIM, nullptr, nullptr);
    }
}

// Round 10
// 930.500 us; speedup vs baseline: 1.8150x; 1.0177x over previous
//
#include <hip/hip_runtime.h>

#define SEQ 8192
#define DIM 1024
#define SM_SCALE 0.03125f   // 1/sqrt(1024)
#define BK 32

typedef unsigned short u16;
typedef float f32x4 __attribute__((ext_vector_type(4)));
typedef short bf16x8 __attribute__((ext_vector_type(8)));
typedef u16   u16x4 __attribute__((ext_vector_type(4)));

typedef __attribute__((address_space(1))) void as1_void;
typedef __attribute__((address_space(3))) void as3_void;

__device__ __forceinline__ u16 f2bf(float x) {
    unsigned u = __float_as_uint(x);
    u += 0x7fffu + ((u >> 16) & 1u);           // round-to-nearest-even
    return (u16)(u >> 16);
}
__device__ __forceinline__ float bf2f(u16 b) {
    return __uint_as_float(((unsigned)b) << 16);
}

// async global->LDS, 16B per lane. LDS dest must be wave-uniform base + lane*16.
__device__ __forceinline__ void gload16(const void* g, void* l) {
    __builtin_amdgcn_global_load_lds((as1_void*)(void*)(size_t)g, (as3_void*)l, 16, 0, 0);
}

#define SBAR() do { __builtin_amdgcn_sched_barrier(0); __builtin_amdgcn_s_barrier(); __builtin_amdgcn_sched_barrier(0); } while (0)
#define VWAIT(n) do { asm volatile("s_waitcnt vmcnt(%0)" :: "i"(n) : "memory"); __builtin_amdgcn_sched_barrier(0); } while (0)

// ---------------------------------------------------------------------------
// Split fp32 -> (hi,lo) bf16, optionally also writing the transposed copies.
// ---------------------------------------------------------------------------
template<bool WRITE_NT>
__launch_bounds__(256)
__global__ void split_kernel(const float* __restrict__ src, int R, int C,
                             u16* __restrict__ hiNT, u16* __restrict__ loNT,
                             u16* __restrict__ hiT,  u16* __restrict__ loT)
{
    __shared__ u16 th[32][33];
    __shared__ u16 tl[32][33];
    int tx = threadIdx.x & 31;
    int ty = threadIdx.x >> 5;           // 0..7
    int c0 = blockIdx.x * 32;
    int r0 = blockIdx.y * 32;
#pragma unroll
    for (int k = 0; k < 4; ++k) {
        int r = ty + k * 8;
        float x = src[(size_t)(r0 + r) * C + c0 + tx];
        u16 h = f2bf(x);
        u16 lo = f2bf(x - bf2f(h));
        if constexpr (WRITE_NT) {
            hiNT[(size_t)(r0 + r) * C + c0 + tx] = h;
            loNT[(size_t)(r0 + r) * C + c0 + tx] = lo;
        }
        th[r][tx] = h;
        tl[r][tx] = lo;
    }
    __syncthreads();
#pragma unroll
    for (int k = 0; k < 4; ++k) {
        int cc = ty + k * 8;
        hiT[(size_t)(c0 + cc) * R + r0 + tx] = th[tx][cc];
        loT[(size_t)(c0 + cc) * R + r0 + tx] = tl[tx][cc];
    }
}

__launch_bounds__(256)
__global__ void zero_kernel(float* __restrict__ p, int n4)
{
    int i = blockIdx.x * 256 + threadIdx.x;
    int stride = gridDim.x * 256;
    for (; i < n4; i += stride) ((f32x4*)p)[i] = (f32x4){0.f, 0.f, 0.f, 0.f};
}

// ---------------------------------------------------------------------------
// Counted-vmcnt double-buffered NT GEMM, split-bf16 fp32 emulation. 8 waves.
//   NA/NB = number of hi/lo tensors on each side:
//     NA=2,NB=2: C = A0B0^T + A0B1^T + A1B0^T  (proj, QK^T - full fp32 emu)
//     NA=1,NB=1: C = A0B0^T                    (PV - P is bf16, Xl dropped:
//                |err| <= max|xl| ~ 0.004 since softmax weights sum to 1)
//   Staging chunks split into B-group (GB/thread, oldest) and A-group (GA).
//   Per tile t: [issue B(t+1)] [fb ds_reads] [vmcnt(GB): A(t) certified]
//   [barrier] [MFR MFMA phases; issue A(t+1) at p=MFR/2] [vmcnt(GA): B(t+1)
//   certified] [barrier].  Loads never drain to 0 in steady state (T4).
//   Source pre-swizzled (G21) -> conflict-free ds_read_b128.
//   XCD decode: x = b&7; TXS x GY supertiles co-resident per XCD (T1).
//   OUTMODE: 0 = fp32 store, 1 = split hi/lo bf16 store, 2 = fp32 atomicAdd
// ---------------------------------------------------------------------------
template<int BM, int BN, int NA, int NB, int OUTMODE>
__launch_bounds__(512)
__global__ void gemmX(const u16* __restrict__ A0, const u16* __restrict__ A1,
                      const u16* __restrict__ B0, const u16* __restrict__ B1,
                      int M, int N, int K, int TXS, int GY, int NKS,
                      float* __restrict__ Cf,
                      u16* __restrict__ Ch, u16* __restrict__ Cl)
{
    constexpr int WR = BM / 2, WC = BN / 4;       // per-wave output tile
    constexpr int MFR = WR / 16, NFR = WC / 16;   // frags per wave
    constexpr int EA = BM * BK, EB = BN * BK;     // elems per tensor tile
    constexpr int OFF_B0 = NA * EA;
    constexpr int BUFSZ = NA * EA + NB * EB;      // elems per K-tile buffer
    constexpr int GA = NA * BM * 4 / 512;         // A 16B-chunks per thread
    constexpr int GB = NB * BN * 4 / 512;         // B 16B-chunks per thread

    __shared__ u16 lds[2 * BUFSZ];

    int tid = threadIdx.x;
    int w = tid >> 6, l = tid & 63;
    int wm = w >> 2, wn = w & 3;                  // 2 x 4 wave grid
    int ln15 = l & 15;
    int kb = l >> 4;                              // k-block of this lane (0..3)

    // ---- XCD-aware block decode ----
    int b = blockIdx.x;
    int x = b & 7, j = b >> 3;
    int span = TXS * GY;
    int g = j / span, r = j % span;
    int cx = x * TXS + (r % TXS);
    int ty = g * GY + (r / TXS);
    int tx = cx / NKS, ks = cx % NKS;
    int m0 = ty * BM, n0 = tx * BN;
    int kbase = ks * (K / NKS);
    const int NT = (K / NKS) / BK;

    // ---- per-thread staging chunk pointers (source pre-swizzled, G21) ----
    const u16* gpA[GA]; int lofA[GA];
#pragma unroll
    for (int i = 0; i < GA; ++i) {
        int c = tid + i * 512;
        const u16* bp; int cc;
        if (NA == 1 || c < BM * 4) { cc = c;          bp = A0 + (size_t)(m0 + (cc >> 2)) * K; }
        else                       { cc = c - BM * 4; bp = A1 + (size_t)(m0 + (cc >> 2)) * K; }
        int row = cc >> 2;
        int cb = (cc & 3) ^ ((row >> 1) & 3);
        gpA[i] = bp + kbase + cb * 8;
        lofA[i] = c * 8;
    }
    const u16* gpB[GB]; int lofB[GB];
#pragma unroll
    for (int i = 0; i < GB; ++i) {
        int c = tid + i * 512;
        const u16* bp; int cc;
        if (NB == 1 || c < BN * 4) { cc = c;          bp = B0 + (size_t)(n0 + (cc >> 2)) * K; }
        else            { cc = c - BN * 4; bp = B1 + (size_t)(n0 + (cc >> 2)) * K; }
        int row = cc >> 2;
        int cb = (cc & 3) ^ ((row >> 1) & 3);
        gpB[i] = bp + kbase + cb * 8;
        lofB[i] = OFF_B0 + c * 8;
    }

    f32x4 acc[MFR][NFR];
#pragma unroll
    for (int i = 0; i < MFR; ++i)
#pragma unroll
        for (int jn = 0; jn < NFR; ++jn) acc[i][jn] = (f32x4){0.f, 0.f, 0.f, 0.f};

    // ---- prologue: stage tile0 (B first, then A); certify B, keep A in flight
#pragma unroll
    for (int i = 0; i < GB; ++i) gload16(gpB[i], lds + lofB[i]);
#pragma unroll
    for (int i = 0; i < GA; ++i) gload16(gpA[i], lds + lofA[i]);
    VWAIT(GA);                    // B(0) done; A(0) (GA chunks) outstanding
    SBAR();

    int kof = BK;
    for (int t = 0; t < NT; ++t) {
        const u16* cur = lds + (t & 1) * BUFSZ;
        u16* nxt = lds + ((t + 1) & 1) * BUFSZ;
        bool pre = (t + 1 < NT);

        // issue B(t+1) early (oldest of next tile's loads)
        if (pre) {
#pragma unroll
            for (int i = 0; i < GB; ++i) gload16(gpB[i] + kof, nxt + lofB[i]);
        }

        // B fragments of tile t (region certified at end of tile t-1)
        bf16x8 fb0[NFR], fb1[(NB == 2) ? NFR : 1];
#pragma unroll
        for (int n = 0; n < NFR; ++n) {
            int rr = wn * WC + n * 16 + ln15;
            int sw = (kb ^ ((rr >> 1) & 3)) << 3;
            fb0[n] = *(const bf16x8*)&cur[OFF_B0 + rr * BK + sw];
            if constexpr (NB == 2)
                fb1[n] = *(const bf16x8*)&cur[OFF_B0 + EB + rr * BK + sw];
        }

        // certify A(t): leave exactly B(t+1)'s GB chunks in flight
        if (pre) VWAIT(GB); else VWAIT(0);
        SBAR();

#pragma unroll
        for (int p = 0; p < MFR; ++p) {
            int rr = wm * WR + p * 16 + ln15;
            int sw = (kb ^ ((rr >> 1) & 3)) << 3;
            bf16x8 fa0 = *(const bf16x8*)&cur[rr * BK + sw];
            bf16x8 fa1;
            if constexpr (NA == 2)
                fa1 = *(const bf16x8*)&cur[EA + rr * BK + sw];

            if (p == MFR / 2 && pre) {     // issue A(t+1) mid-compute
#pragma unroll
                for (int i = 0; i < GA; ++i) gload16(gpA[i] + kof, nxt + lofA[i]);
            }

            __builtin_amdgcn_s_setprio(1);
#pragma unroll
            for (int n = 0; n < NFR; ++n) {
                acc[p][n] = __builtin_amdgcn_mfma_f32_16x16x32_bf16(fa0, fb0[n], acc[p][n], 0, 0, 0);
                if constexpr (NB == 2)
                    acc[p][n] = __builtin_amdgcn_mfma_f32_16x16x32_bf16(fa0, fb1[n], acc[p][n], 0, 0, 0);
                if constexpr (NA == 2)
                    acc[p][n] = __builtin_amdgcn_mfma_f32_16x16x32_bf16(fa1, fb0[n], acc[p][n], 0, 0, 0);
            }
            __builtin_amdgcn_s_setprio(0);
        }

        // certify B(t+1): leave exactly A(t+1)'s GA chunks in flight
        if (pre) VWAIT(GA); else VWAIT(0);
        SBAR();
        kof += BK;
    }

    // ---- epilogue. C/D frag map (m89): col = lane&15, row = (lane>>4)*4+q ----
    int orow = m0 + wm * WR + (l >> 4) * 4;
    int ocol = n0 + wn * WC + ln15;
#pragma unroll
    for (int m = 0; m < MFR; ++m)
#pragma unroll
        for (int n = 0; n < NFR; ++n)
#pragma unroll
            for (int q = 0; q < 4; ++q) {
                size_t idx = (size_t)(orow + m * 16 + q) * N + (ocol + n * 16);
                float v = acc[m][n][q];
                if constexpr (OUTMODE == 0) {
                    Cf[idx] = v;
                } else if constexpr (OUTMODE == 1) {
                    u16 h = f2bf(v);
                    Ch[idx] = h;
                    Cl[idx] = f2bf(v - bf2f(h));
                } else {
                    atomicAdd(&Cf[idx], v);
                }
            }
}

// ---------------------------------------------------------------------------
// Row softmax: P[r][:] = softmax(S[r][:] * SM_SCALE), fp32 -> bf16
// ---------------------------------------------------------------------------
__launch_bounds__(256)
__global__ void softmax_kernel(const float* __restrict__ S, u16* __restrict__ P)
{
    size_t row = blockIdx.x;
    const f32x4* s4 = (const f32x4*)(S + row * SEQ);
    int t = threadIdx.x;
    int w = t >> 6, l = t & 63;

    float v[32];
    float mx = -3.4e38f;
#pragma unroll
    for (int i = 0; i < 8; ++i) {
        f32x4 xv = s4[t + i * 256];
#pragma unroll
        for (int jj = 0; jj < 4; ++jj) {
            float f = xv[jj] * SM_SCALE;
            v[i * 4 + jj] = f;
            mx = fmaxf(mx, f);
        }
    }
#pragma unroll
    for (int off = 32; off; off >>= 1) mx = fmaxf(mx, __shfl_xor(mx, off));

    __shared__ float redm[4];
    __shared__ float reds[4];
    if (l == 0) redm[w] = mx;
    __syncthreads();
    mx = fmaxf(fmaxf(redm[0], redm[1]), fmaxf(redm[2], redm[3]));

    float sum = 0.f;
#pragma unroll
    for (int i = 0; i < 32; ++i) {
        v[i] = __expf(v[i] - mx);
        sum += v[i];
    }
#pragma unroll
    for (int off = 32; off; off >>= 1) sum += __shfl_xor(sum, off);
    if (l == 0) reds[w] = sum;
    __syncthreads();
    sum = reds[0] + reds[1] + reds[2] + reds[3];
    float inv = 1.f / sum;

    u16* p = P + row * SEQ;
#pragma unroll
    for (int i = 0; i < 8; ++i) {
        u16x4 o;
#pragma unroll
        for (int jj = 0; jj < 4; ++jj) o[jj] = f2bf(v[i * 4 + jj] * inv);
        *(u16x4*)&p[4 * (t + i * 256)] = o;
    }
}

// ---------------------------------------------------------------------------
extern "C" void kernel_launch(void* const* d_in, const int* in_sizes, int n_in,
                              void* d_out, int out_size, void* d_ws, size_t ws_size,
                              hipStream_t stream)
{
    const float* X  = (const float*)d_in[0];
    const float* Wq = (const float*)d_in[1];
    const float* Wk = (const float*)d_in[2];
    float* out = (float*)d_out;
    char* ws = (char*)d_ws;

    const size_t XE = (size_t)SEQ * DIM;
    const size_t WE = (size_t)DIM * DIM;

    u16* Xh   = (u16*)ws;
    u16* Xl   = Xh + XE;
    u16* XhT  = Xl + XE;
    u16* XlT  = XhT + XE;
    u16* WqhT = XlT + XE;
    u16* WqlT = WqhT + WE;
    u16* WkhT = WqlT + WE;
    u16* WklT = WkhT + WE;
    u16* Qh   = WklT + WE;
    u16* Ql   = Qh + XE;
    u16* Kh   = Ql + XE;
    u16* Kl   = Kh + XE;
    char* dyn = (char*)(Kl + XE);

    size_t fixed = (size_t)(dyn - ws);
    size_t avail = ws_size > fixed ? ws_size - fixed : 0;

    // chunk rows: S fp32 (32KB/row) + P bf16 (16KB/row).
    // CH = 2048 -> QK/PV grids are exactly 256 blocks = 1 block/CU, 1 round.
    size_t perrow = (size_t)SEQ * 6;
    long long chll = (long long)(avail / perrow);
    int CH = chll > SEQ ? SEQ : (int)chll;
    if (CH >= 2048) CH = 2048;
    else { CH &= ~255; if (CH < 256) CH = 256; }

    float* Sbuf = (float*)dyn;
    u16*   Pbuf = (u16*)(dyn + (size_t)CH * SEQ * sizeof(float));

    // 1) splits
    split_kernel<true ><<<dim3(DIM / 32, SEQ / 32), 256, 0, stream>>>(X, SEQ, DIM, Xh, Xl, XhT, XlT);
    split_kernel<false><<<dim3(DIM / 32, DIM / 32), 256, 0, stream>>>(Wq, DIM, DIM, nullptr, nullptr, WqhT, WqlT);
    split_kernel<false><<<dim3(DIM / 32, DIM / 32), 256, 0, stream>>>(Wk, DIM, DIM, nullptr, nullptr, WkhT, WklT);

    // 2) projections: Q = X@Wq, K = X@Wk (fp32-accurate hi/lo bf16 out)
    //    tile 256x128, grid 8tx*32ty=256, XCD owns 1 tx column (W-set L2-res)
    gemmX<256, 128, 2, 2, 1><<<dim3(256), 512, 0, stream>>>(
        Xh, Xl, WqhT, WqlT, SEQ, DIM, DIM, 1, 32, 1, nullptr, Qh, Ql);
    gemmX<256, 128, 2, 2, 1><<<dim3(256), 512, 0, stream>>>(
        Xh, Xl, WkhT, WklT, SEQ, DIM, DIM, 1, 32, 1, nullptr, Kh, Kl);

    // 3) zero the output (PV accumulates via atomicAdd)
    zero_kernel<<<dim3(512), 256, 0, stream>>>(out, (int)(XE / 4));

    // 4) chunked: S = Q K^T ; P = softmax ; out += P Xh (split-K=8)
    for (int r0 = 0; r0 < SEQ; r0 += CH) {
        int ch = (SEQ - r0 < CH) ? (SEQ - r0) : CH;
        int nty = ch / 256;

        // QK^T: tile 256x256, 3-term, TXS=4, GY=8 -> grid 256 at CH=2048
        gemmX<256, 256, 2, 2, 0><<<dim3(32 * nty), 512, 0, stream>>>(
            Qh + (size_t)r0 * DIM, Ql + (size_t)r0 * DIM, Kh, Kl,
            ch, SEQ, DIM, 4, 8, 1, Sbuf, nullptr, nullptr);

        softmax_kernel<<<ch, 256, 0, stream>>>(Sbuf, Pbuf);

        // PV: out += P @ Xh^T. tile 256x256, 1-term, split-K=8 ->
        // 4tx*8ks*8ty = 256 blocks; each P-tile read by only 4 tx (was 8);
        // XCD's X^T panel (2MB) L2-resident
        gemmX<256, 256, 1, 1, 2><<<dim3(32 * nty), 512, 0, stream>>>(
            Pbuf, nullptr, XhT, nullptr,
            ch, DIM, SEQ, 4, 8, 8, out + (size_t)r0 * DIM, nullptr, nullptr);
    }
}